// Round 7
// baseline (537.892 us; speedup 1.0000x reference)
//
#include <hip/hip_runtime.h>
#include <stdint.h>

#define NN 4096
#define NE 65536
#define LEAKY 0.01f
#define BN_EPS 1e-5f
#define DSTRIDE 96   // padded adjacency stride (mean deg 16, 12+ sigma margin)

typedef float f32x4 __attribute__((ext_vector_type(4)));
typedef __bf16 bf16x8 __attribute__((ext_vector_type(8)));
typedef unsigned short u16x8 __attribute__((ext_vector_type(8)));

static __device__ __forceinline__ unsigned short f2bf(float v) {
  unsigned int u = __float_as_uint(v);
  u += 0x7fff + ((u >> 16) & 1);   // RNE; inputs are finite
  return (unsigned short)(u >> 16);
}

typedef __attribute__((address_space(1))) void gvoid;
typedef __attribute__((address_space(3))) void lvoid;

static __device__ __forceinline__ void async16(const void* g, void* l) {
  __builtin_amdgcn_global_load_lds((gvoid*)(uintptr_t)g,
                                   (lvoid*)(uint32_t)(uintptr_t)l, 16, 0, 0);
}

// ======================= setup: W packs + adjacency build ===================
// bf16 GEMM-input layout: within each 64-col K-group, row r's 16B block b is
// stored at block (b + r) & 7 (LDS de-conflict rotation; GEMM unrotates).
// x_in is never packed/staged: layer-1 GEMM loads A fragments global->reg.

static __device__ __forceinline__ void pack_w_seg(int lblk, const float* __restrict__ Wl,
                                                  const float* __restrict__ Wr,
                                                  unsigned short* __restrict__ dst,
                                                  int Fout, int Fin, int Kp, int Np) {
  int nb = Kp >> 3;
  int idx = lblk * 256 + threadIdx.x;
  if (idx >= Np * nb) return;
  int row = idx / nb, kb = idx - row * nb;
  int g = kb >> 3, b = kb & 7;
  int dkb = (g << 3) | ((b + row) & 7);
  const float* src = nullptr;
  if (row < Fout)          src = Wl + (size_t)row * Fin;
  else if (row < 2 * Fout) src = Wr + (size_t)(row - Fout) * Fin;
  u16x8 st;
#pragma unroll
  for (int o = 0; o < 8; ++o) {
    int k = kb * 8 + o;
    float v = (src && k < Fin) ? src[k] : 0.f;
    st[o] = f2bf(v);
  }
  *(u16x8*)&dst[(size_t)row * Kp + dkb * 8] = st;
}

#define ADJ_BLK    256   // 65536/256 (first: atomic tail overlaps pack work)
#define PW1_BLK   2660   // 640*1064/256
#define PW2_BLK     60
#define PW3_BLK     24
#define PW4_BLK      8
#define SETUP_BLK (ADJ_BLK + PW1_BLK + PW2_BLK + PW3_BLK + PW4_BLK)

__global__ __launch_bounds__(256) void setup_all(
    const int* __restrict__ esrc, const int* __restrict__ edst,
    const float* __restrict__ W1l, const float* __restrict__ W1r,
    const float* __restrict__ W2l, const float* __restrict__ W2r,
    const float* __restrict__ W3l, const float* __restrict__ W3r,
    const float* __restrict__ W4l, const float* __restrict__ W4r,
    unsigned short* __restrict__ wb1, unsigned short* __restrict__ wb2,
    unsigned short* __restrict__ wb3, unsigned short* __restrict__ wb4,
    int* __restrict__ deg, int* __restrict__ eix) {
  int blk = blockIdx.x;
  if (blk < ADJ_BLK) {
    // padded-adjacency build: deg pre-zeroed by memset before this kernel
    int e = blk * 256 + threadIdx.x;
    int d = edst[e];
    int pos = atomicAdd(&deg[d], 1);
    if (pos < DSTRIDE) eix[(size_t)d * DSTRIDE + pos] = esrc[e];
  } else if (blk < ADJ_BLK + PW1_BLK) {
    pack_w_seg(blk - ADJ_BLK, W1l, W1r, wb1, 320, 8500, 8512, 640);
  } else if (blk < ADJ_BLK + PW1_BLK + PW2_BLK) {
    pack_w_seg(blk - ADJ_BLK - PW1_BLK, W2l, W2r, wb2, 180, 320, 320, 384);
  } else if (blk < ADJ_BLK + PW1_BLK + PW2_BLK + PW3_BLK) {
    pack_w_seg(blk - ADJ_BLK - PW1_BLK - PW2_BLK, W3l, W3r, wb3, 90, 180, 192, 256);
  } else {
    pack_w_seg(blk - ADJ_BLK - PW1_BLK - PW2_BLK - PW3_BLK, W4l, W4r, wb4,
               50, 90, 128, 128);
  }
}

// ======= layer-1 GEMM: A fragments loaded global->reg (no A LDS at all) =====
// C = A[M,8500->8512] @ B[N,8512]^T, K-split slab partials over blockIdx.z.
// A-fragment geometry: lane (l16,quad) of wave w holds rows wm+i*16+l16,
// cols kt*64+(4kh+quad)*8..+7 -- across a wave: 16 rows x 128 contiguous B
// per (i,kh) = fully-coalesced dwordx4 pairs. Prefetch A(kt+1) into 64 regs
// during step kt's MFMAs; cvt fp32->bf16 after the barrier.
// B: bf16 packed (rotated), async16 into double-buffered 16KB LDS.
// ONE __syncthreads per K-step; compiler-scheduled (R4 lesson: no fences).
__global__ __launch_bounds__(256) void gemm_areg(const float* __restrict__ X,
                                                 const unsigned short* __restrict__ B,
                                                 float* __restrict__ C, int N, int M) {
  const int K = 8512, KS = 133, FIN = 8500;
  __shared__ unsigned short Bs[2][128 * 64];   // 32 KB

  const int t = threadIdx.x;
  const int bm = blockIdx.x, bn = blockIdx.y;
  const int lane = t & 63;
  const int wave = t >> 6;
  const int wm = (wave & 1) * 64, wn = (wave >> 1) * 64;
  const int l16 = lane & 15, quad = lane >> 4;

  const int gz = (int)gridDim.z, z = (int)blockIdx.z;
  const int per = KS / gz, rem = KS % gz;
  const int k0 = z * per + (z < rem ? z : rem);
  const int k1 = k0 + per + (z < rem ? 1 : 0);

  f32x4 acc[4][4];
#pragma unroll
  for (int i = 0; i < 4; ++i)
#pragma unroll
    for (int j = 0; j < 4; ++j) acc[i][j] = (f32x4){0.f, 0.f, 0.f, 0.f};

  // A row bases (col offset quad*8 baked in)
  const float* Arow[4];
#pragma unroll
  for (int i = 0; i < 4; ++i)
    Arow[i] = X + (size_t)(bm * 128 + wm + i * 16 + l16) * FIN + quad * 8;

  f32x4 pf[4][2][2];      // prefetch: [i][kh][16B half]
  bf16x8 curA[4][2];      // converted fragments for current step

  auto loadA = [&](int kt) {
    if (kt < 132) {
#pragma unroll
      for (int i = 0; i < 4; ++i) {
        const float* p = Arow[i] + (size_t)kt * 64;
        pf[i][0][0] = *(const f32x4*)p;
        pf[i][0][1] = *(const f32x4*)(p + 4);
        pf[i][1][0] = *(const f32x4*)(p + 32);
        pf[i][1][1] = *(const f32x4*)(p + 36);
      }
    } else {   // K tail: per-element guard against FIN=8500
#pragma unroll
      for (int i = 0; i < 4; ++i)
#pragma unroll
        for (int kh = 0; kh < 2; ++kh)
#pragma unroll
          for (int h = 0; h < 2; ++h) {
            f32x4 v = (f32x4){0.f, 0.f, 0.f, 0.f};
            int cb = kt * 64 + kh * 32 + quad * 8 + h * 4;
#pragma unroll
            for (int o = 0; o < 4; ++o)
              if (cb + o < FIN) v[o] = Arow[i][(size_t)kt * 64 + kh * 32 + h * 4 + o];
            pf[i][kh][h] = v;
          }
    }
  };
  auto cvtA = [&]() {
#pragma unroll
    for (int i = 0; i < 4; ++i)
#pragma unroll
      for (int kh = 0; kh < 2; ++kh) {
        bf16x8 c;
#pragma unroll
        for (int o = 0; o < 4; ++o) {
          c[o]     = (__bf16)pf[i][kh][0][o];
          c[o + 4] = (__bf16)pf[i][kh][1][o];
        }
        curA[i][kh] = c;
      }
  };
  // B staging (identical geometry to gemm_bt)
  const int srow = t >> 3;
  const int scol = (t & 7) * 8;
  const unsigned short* Bbase = B + (size_t)(bn * 128) * K + scol;
  auto stageB = [&](int kt, int bb) {
    unsigned short* Bd = Bs[bb];
#pragma unroll
    for (int p = 0; p < 4; ++p) {
      int row = p * 32 + srow;
      async16(Bbase + (size_t)row * K + kt * 64, &Bd[row * 64 + scol]);
    }
  };

  // prologue
  loadA(k0);
  stageB(k0, 0);
  __syncthreads();
  cvtA();

  int bb = 0;
  for (int kt = k0; kt < k1; ++kt) {
    bool more = (kt + 1 < k1);
    if (more) {
      loadA(kt + 1);            // 16 dwordx4 in flight under MFMA
      stageB(kt + 1, bb ^ 1);
    }
#pragma unroll
    for (int kh = 0; kh < 2; ++kh) {
      const int s8 = ((kh * 4 + quad + l16) & 7) * 8;   // B unrotate
      bf16x8 bfr[4];
#pragma unroll
      for (int j = 0; j < 4; ++j)
        bfr[j] = *(const bf16x8*)&Bs[bb][(wn + j * 16 + l16) * 64 + s8];
#pragma unroll
      for (int i = 0; i < 4; ++i)
#pragma unroll
        for (int j = 0; j < 4; ++j)
          acc[i][j] = __builtin_amdgcn_mfma_f32_16x16x32_bf16(curA[i][kh], bfr[j], acc[i][j], 0, 0, 0);
    }
    if (more) {
      __syncthreads();          // B(kt+1) visible; drains A loads too (old)
      cvtA();                   // fp32 -> bf16 for kt+1
      bb ^= 1;
    }
  }

  float* Cb = C + (size_t)blockIdx.z * M * N;
#pragma unroll
  for (int i = 0; i < 4; ++i) {
    int rbase = bm * 128 + wm + i * 16 + quad * 4;
#pragma unroll
    for (int j = 0; j < 4; ++j) {
      int col = bn * 128 + wn + j * 16 + l16;
      float* cp = Cb + (size_t)rbase * N + col;
#pragma unroll
      for (int r = 0; r < 4; ++r) cp[(size_t)r * N] = acc[i][j][r];
    }
  }
}

// ---------------- bf16 MFMA GEMM (layers 2-4): C = A[M,K] @ B[N,K]^T --------
__global__ __launch_bounds__(256) void gemm_bt(const unsigned short* __restrict__ A,
                                               const unsigned short* __restrict__ B,
                                               float* __restrict__ C, int N, int K,
                                               int M) {
  __shared__ unsigned short smem[2 * 128 * 64];
  unsigned short* As = smem;
  unsigned short* Bs = smem + 128 * 64;

  const int t = threadIdx.x;
  const int bm = blockIdx.x, bn = blockIdx.y;
  const int lane = t & 63;
  const int wave = t >> 6;
  const int wm = (wave & 1) * 64, wn = (wave >> 1) * 64;
  const int l16 = lane & 15, quad = lane >> 4;

  const int ksteps = K >> 6;

  f32x4 acc[4][4];
#pragma unroll
  for (int i = 0; i < 4; ++i)
#pragma unroll
    for (int j = 0; j < 4; ++j) acc[i][j] = (f32x4){0.f, 0.f, 0.f, 0.f};

  const int srow = t >> 3;
  const int scol = (t & 7) * 8;
  const unsigned short* Abase = A + (size_t)(bm * 128) * K + scol;
  const unsigned short* Bbase = B + (size_t)(bn * 128) * K + scol;

  for (int kt = 0; kt < ksteps; ++kt) {
    const unsigned short* Ag = Abase + kt * 64;
    const unsigned short* Bg = Bbase + kt * 64;
#pragma unroll
    for (int p = 0; p < 4; ++p) {
      int row = p * 32 + srow;
      async16(Ag + (size_t)row * K, &As[row * 64 + scol]);
    }
#pragma unroll
    for (int p = 0; p < 4; ++p) {
      int row = p * 32 + srow;
      async16(Bg + (size_t)row * K, &Bs[row * 64 + scol]);
    }
    __syncthreads();
#pragma unroll
    for (int kh = 0; kh < 2; ++kh) {
      const int s8 = ((kh * 4 + quad + l16) & 7) * 8;   // unrotate
      bf16x8 af[4], bfr[4];
#pragma unroll
      for (int i = 0; i < 4; ++i)
        af[i] = *(const bf16x8*)&As[(wm + i * 16 + l16) * 64 + s8];
#pragma unroll
      for (int j = 0; j < 4; ++j)
        bfr[j] = *(const bf16x8*)&Bs[(wn + j * 16 + l16) * 64 + s8];
#pragma unroll
      for (int i = 0; i < 4; ++i)
#pragma unroll
        for (int j = 0; j < 4; ++j)
          acc[i][j] = __builtin_amdgcn_mfma_f32_16x16x32_bf16(af[i], bfr[j], acc[i][j], 0, 0, 0);
    }
    __syncthreads();
  }

#pragma unroll
  for (int i = 0; i < 4; ++i) {
    int rbase = bm * 128 + wm + i * 16 + quad * 4;
#pragma unroll
    for (int j = 0; j < 4; ++j) {
      int col = bn * 128 + wn + j * 16 + l16;
      float* cp = C + (size_t)rbase * N + col;
#pragma unroll
      for (int r = 0; r < 4; ++r) cp[(size_t)r * N] = acc[i][j][r];
    }
  }
}

// sum nz K-split partials in place (y = partial 0); grid exact NN*640/4/256
__global__ void reduceN(float* __restrict__ y, int nz) {
  int idx = blockIdx.x * 256 + threadIdx.x;
  f32x4* p = (f32x4*)y;
  const int S = NN * 640 / 4;
  f32x4 v = p[idx];
  for (int sl = 1; sl < nz; ++sl) v += p[idx + (size_t)sl * S];
  p[idx] = v;
}

// ---------------- fused mean-aggregate + root + bias + leaky ----------------
// block (64,4): tx = feature quad, ty = edge stripe; padded adjacency.
// In-block loop over 64-f4 feature stripes (stages edge list once per node).
__global__ __launch_bounds__(256) void sage_agg(
    const float* __restrict__ y, const int* __restrict__ deg,
    const int* __restrict__ eix, const float* __restrict__ bias,
    float* __restrict__ z, int F, int ldy) {
  int i = blockIdx.x;
  int tx = threadIdx.x, ty = threadIdx.y;
  __shared__ int se[DSTRIDE];
  __shared__ float red[3][64][4];
  int d = deg[i]; if (d > DSTRIDE) d = DSTRIDE;
  // stage edge list (d <= 96 -> one pass with 256 threads)
  {
    int lt = ty * 64 + tx;
    if (lt < d) se[lt] = eix[(size_t)i * DSTRIDE + lt];
  }
  __syncthreads();
  int nfb = (F + 255) >> 8;
  for (int fb = 0; fb < nfb; ++fb) {
    int f4 = (fb * 64 + tx) * 4;
    bool active = (f4 < F);
    f32x4 s = {0.f, 0.f, 0.f, 0.f};
    if (active) {
      const float* yb = y + f4;
      int e = ty;
      for (; e + 4 < d; e += 8) {   // 2x unroll: two independent loads in flight
        f32x4 a = *(const f32x4*)&yb[(size_t)se[e] * ldy];
        f32x4 b = *(const f32x4*)&yb[(size_t)se[e + 4] * ldy];
        s += a; s += b;
      }
      if (e < d) s += *(const f32x4*)&yb[(size_t)se[e] * ldy];
    }
    if (ty > 0) *(f32x4*)red[ty - 1][tx] = s;
    __syncthreads();
    if (ty == 0 && active) {
      s += *(const f32x4*)red[0][tx];
      s += *(const f32x4*)red[1][tx];
      s += *(const f32x4*)red[2][tx];
      float inv = 1.f / (float)(d > 1 ? d : 1);
      int cnt = F - f4; if (cnt > 4) cnt = 4;
      const float* yr = &y[(size_t)i * ldy + F + f4];
      float* zo = &z[(size_t)i * F + f4];
      for (int j = 0; j < cnt; ++j) {
        float w = s[j] * inv + yr[j] + bias[f4 + j];
        zo[j] = (w >= 0.f) ? w : LEAKY * w;
      }
    }
    if (fb + 1 < nfb) __syncthreads();   // red reuse barrier
  }
}

// ---------------- batchnorm: row-major partial sums + fused finalize --------

__global__ __launch_bounds__(256) void bn_part(const float* __restrict__ z,
                                               float* __restrict__ sums, int F) {
  int tx = threadIdx.x, ty = threadIdx.y;      // block (64,4)
  int f = blockIdx.x * 64 + tx;
  float s = 0.f, s2 = 0.f;
  if (f < F) {
    int r0 = blockIdx.y * 512 + ty * 128;
    for (int j = 0; j < 128; ++j) {
      float v = z[(size_t)(r0 + j) * F + f];
      s += v; s2 += v * v;
    }
  }
  __shared__ float ls[4][64], ls2[4][64];
  ls[ty][tx] = s; ls2[ty][tx] = s2;
  __syncthreads();
  if (ty == 0 && f < F) {
    float S  = ls[0][tx] + ls[1][tx] + ls[2][tx] + ls[3][tx];
    float S2 = ls2[0][tx] + ls2[1][tx] + ls2[2][tx] + ls2[3][tx];
    atomicAdd(&sums[f], S);
    atomicAdd(&sums[F + f], S2);
  }
}

// normalize -> next layer's rotated bf16 input (finalizes BN from sums)
__global__ void bn_norm8(const float* __restrict__ z, const float* __restrict__ sums,
                         unsigned short* __restrict__ xout, int F, int Kp) {
  int nb = Kp >> 3;
  int idx = blockIdx.x * 256 + threadIdx.x;    // exact grid
  int row = idx / nb, kb = idx - row * nb;
  int g = kb >> 3, b = kb & 7;
  int dkb = (g << 3) | ((b + row) & 7);
  u16x8 st;
#pragma unroll
  for (int o = 0; o < 8; ++o) {
    int k = kb * 8 + o;
    float v = 0.f;
    if (k < F) {
      float m  = sums[k] * (1.f / NN);
      float var = sums[F + k] * (1.f / NN) - m * m;
      float rs = rsqrtf(var + BN_EPS);
      v = (z[(size_t)row * F + k] - m) * rs;
    }
    st[o] = f2bf(v);
  }
  *(u16x8*)&xout[(size_t)row * Kp + dkb * 8] = st;
}

// ---------------- pool (BN folded in) + 3 FC layers ----------------
__global__ void pool_fc(const float* __restrict__ z,  // [4096, 50] pre-BN
                        const float* __restrict__ sums,
                        const float* __restrict__ Wf1, const float* __restrict__ bf1,
                        const float* __restrict__ Wf2, const float* __restrict__ bf2,
                        const float* __restrict__ Wf3, const float* __restrict__ bf3,
                        float* __restrict__ out) {
  __shared__ float pool[50];
  __shared__ float h1[32], h2[16];
  int b = blockIdx.x, t = threadIdx.x;  // 64 threads
  if (t < 50) {
    float s = 0.f;
    for (int r = 0; r < 256; ++r) s += z[(size_t)(b * 256 + r) * 50 + t];
    float m  = sums[t] * (1.f / NN);
    float var = sums[50 + t] * (1.f / NN) - m * m;
    float rs = rsqrtf(var + BN_EPS);
    pool[t] = (s - 256.f * m) * rs;   // sum of normalized = (sum - n*m)*rs
  }
  __syncthreads();
  if (t < 32) {
    float s = bf1[t];
    for (int f = 0; f < 50; ++f) s += pool[f] * Wf1[t * 50 + f];
    h1[t] = s;
  }
  __syncthreads();
  if (t < 16) {
    float s = bf2[t];
    for (int f = 0; f < 32; ++f) s += h1[f] * Wf2[t * 32 + f];
    h2[t] = s;
  }
  __syncthreads();
  if (t == 0) {
    float s = bf3[0];
    for (int f = 0; f < 16; ++f) s += h2[f] * Wf3[f];
    out[b] = s;
  }
}

// ---------------- host ----------------

extern "C" void kernel_launch(void* const* d_in, const int* in_sizes, int n_in,
                              void* d_out, int out_size, void* d_ws, size_t ws_size,
                              hipStream_t stream) {
  const float* x_in = (const float*)d_in[0];
  const int* ei = (const int*)d_in[1];      // int32 per harness contract
  const float* W1l = (const float*)d_in[2];
  const float* b1  = (const float*)d_in[3];
  const float* W1r = (const float*)d_in[4];
  const float* W2l = (const float*)d_in[5];
  const float* b2  = (const float*)d_in[6];
  const float* W2r = (const float*)d_in[7];
  const float* W3l = (const float*)d_in[8];
  const float* b3  = (const float*)d_in[9];
  const float* W3r = (const float*)d_in[10];
  const float* W4l = (const float*)d_in[11];
  const float* b4  = (const float*)d_in[12];
  const float* W4r = (const float*)d_in[13];
  const float* Wf1 = (const float*)d_in[14];
  const float* bf1 = (const float*)d_in[15];
  const float* Wf2 = (const float*)d_in[16];
  const float* bf2 = (const float*)d_in[17];
  const float* Wf3 = (const float*)d_in[18];
  const float* bf3 = (const float*)d_in[19];
  float* out = (float*)d_out;
  (void)in_sizes; (void)n_in; (void)out_size;

  char* ws = (char*)d_ws;
  size_t off = 0;
  auto alloc = [&](size_t bytes) -> void* {
    void* p = ws + off;
    off = (off + bytes + 255) & ~(size_t)255;
    return p;
  };
  unsigned short* xbf = (unsigned short*)alloc((size_t)NN * 320 * 2);  // layers 2-4 A
  unsigned short* wb1 = (unsigned short*)alloc((size_t)640 * 8512 * 2);
  unsigned short* wb2 = (unsigned short*)alloc((size_t)384 * 320 * 2);
  unsigned short* wb3 = (unsigned short*)alloc((size_t)256 * 192 * 2);
  unsigned short* wb4 = (unsigned short*)alloc((size_t)128 * 128 * 2);
  float* z    = (float*)alloc((size_t)NN * 320 * 4);
  // contiguous zero region: deg + bnsum
  int* deg    = (int*)alloc(NN * 4);
  float* bnsum = (float*)alloc(1280 * 4);
  int* eix    = (int*)alloc((size_t)NN * DSTRIDE * 4);
  const size_t YS = (size_t)NN * 640 * 4;   // one K-split slab
  float* y = (float*)(ws + off);            // y slabs last
  int nz = (off + 8 * YS <= ws_size) ? 8 : 4;
  if (off + (size_t)nz * YS > ws_size) return;
  float* bns1 = bnsum;             // 2*320
  float* bns2 = bnsum + 640;       // 2*180
  float* bns3 = bnsum + 1000;      // 2*90
  float* bns4 = bnsum + 1180;      // 2*50

  hipMemsetAsync(deg, 0, NN * 4 + 1280 * 4, stream);

  setup_all<<<dim3(SETUP_BLK), dim3(256), 0, stream>>>(
      ei, ei + NE, W1l, W1r, W2l, W2r, W3l, W3r, W4l, W4r,
      wb1, wb2, wb3, wb4, deg, eix);

  // ---- layer 1: K=8512 (A global->reg fragments), K-split nz + reduce ----
  gemm_areg<<<dim3(32, 5, nz), dim3(256), 0, stream>>>(x_in, wb1, y, 640, NN);
  reduceN<<<dim3(NN * 640 / 4 / 256), dim3(256), 0, stream>>>(y, nz);
  sage_agg<<<dim3(NN), dim3(64, 4), 0, stream>>>(y, deg, eix, b1, z, 320, 640);
  bn_part<<<dim3(5, 8), dim3(64, 4), 0, stream>>>(z, bns1, 320);
  bn_norm8<<<dim3(NN * 40 / 256), dim3(256), 0, stream>>>(z, bns1, xbf, 320, 320);

  // ---- layer 2: K=320, N=384 ----
  gemm_bt<<<dim3(32, 3, 1), dim3(256), 0, stream>>>(xbf, wb2, y, 384, 320, NN);
  sage_agg<<<dim3(NN), dim3(64, 4), 0, stream>>>(y, deg, eix, b2, z, 180, 384);
  bn_part<<<dim3(3, 8), dim3(64, 4), 0, stream>>>(z, bns2, 180);
  bn_norm8<<<dim3(NN * 24 / 256), dim3(256), 0, stream>>>(z, bns2, xbf, 180, 192);

  // ---- layer 3: K=192, N=256 ----
  gemm_bt<<<dim3(32, 2, 1), dim3(256), 0, stream>>>(xbf, wb3, y, 256, 192, NN);
  sage_agg<<<dim3(NN), dim3(64, 4), 0, stream>>>(y, deg, eix, b3, z, 90, 256);
  bn_part<<<dim3(2, 8), dim3(64, 4), 0, stream>>>(z, bns3, 90);
  bn_norm8<<<dim3(NN * 16 / 256), dim3(256), 0, stream>>>(z, bns3, xbf, 90, 128);

  // ---- layer 4: K=128, N=128 ----
  gemm_bt<<<dim3(32, 1, 1), dim3(256), 0, stream>>>(xbf, wb4, y, 128, 128, NN);
  sage_agg<<<dim3(NN), dim3(64, 4), 0, stream>>>(y, deg, eix, b4, z, 50, 128);
  bn_part<<<dim3(1, 8), dim3(64, 4), 0, stream>>>(z, bns4, 50);

  // ---- pool (BN folded) + FC ----
  pool_fc<<<dim3(16), dim3(64), 0, stream>>>(z, bns4, Wf1, bf1, Wf2, bf2, Wf3, bf3, out);
}

// Round 8
// 505.608 us; speedup vs baseline: 1.0639x; 1.0639x over previous
//
#include <hip/hip_runtime.h>
#include <stdint.h>

#define NN 4096
#define NE 65536
#define LEAKY 0.01f
#define BN_EPS 1e-5f
#define DSTRIDE 96   // padded adjacency stride (mean deg 16, 12+ sigma margin)

typedef float f32x4 __attribute__((ext_vector_type(4)));
typedef __bf16 bf16x8 __attribute__((ext_vector_type(8)));
typedef unsigned short u16x8 __attribute__((ext_vector_type(8)));

static __device__ __forceinline__ unsigned short f2bf(float v) {
  unsigned int u = __float_as_uint(v);
  u += 0x7fff + ((u >> 16) & 1);   // RNE; inputs are finite
  return (unsigned short)(u >> 16);
}

typedef __attribute__((address_space(1))) void gvoid;
typedef __attribute__((address_space(3))) void lvoid;

static __device__ __forceinline__ void async16(const void* g, void* l) {
  __builtin_amdgcn_global_load_lds((gvoid*)(uintptr_t)g,
                                   (lvoid*)(uint32_t)(uintptr_t)l, 16, 0, 0);
}

// ======================= setup: W packs + adjacency build ===================
// bf16 GEMM-input layout: within each 64-col K-group, row r's 16B block b is
// stored at block (b + r) & 7 (LDS de-conflict rotation; GEMM unrotates).
// x_in is never packed: layer-1 GEMM stages fp32 A via async16 (rotated src).

static __device__ __forceinline__ void pack_w_seg(int lblk, const float* __restrict__ Wl,
                                                  const float* __restrict__ Wr,
                                                  unsigned short* __restrict__ dst,
                                                  int Fout, int Fin, int Kp, int Np) {
  int nb = Kp >> 3;
  int idx = lblk * 256 + threadIdx.x;
  if (idx >= Np * nb) return;
  int row = idx / nb, kb = idx - row * nb;
  int g = kb >> 3, b = kb & 7;
  int dkb = (g << 3) | ((b + row) & 7);
  const float* src = nullptr;
  if (row < Fout)          src = Wl + (size_t)row * Fin;
  else if (row < 2 * Fout) src = Wr + (size_t)(row - Fout) * Fin;
  u16x8 st;
#pragma unroll
  for (int o = 0; o < 8; ++o) {
    int k = kb * 8 + o;
    float v = (src && k < Fin) ? src[k] : 0.f;
    st[o] = f2bf(v);
  }
  *(u16x8*)&dst[(size_t)row * Kp + dkb * 8] = st;
}

#define ADJ_BLK    256   // 65536/256 (first: atomic tail overlaps pack work)
#define PW1_BLK   2660   // 640*1064/256
#define PW2_BLK     60
#define PW3_BLK     24
#define PW4_BLK      8
#define SETUP_BLK (ADJ_BLK + PW1_BLK + PW2_BLK + PW3_BLK + PW4_BLK)

__global__ __launch_bounds__(256) void setup_all(
    const int* __restrict__ esrc, const int* __restrict__ edst,
    const float* __restrict__ W1l, const float* __restrict__ W1r,
    const float* __restrict__ W2l, const float* __restrict__ W2r,
    const float* __restrict__ W3l, const float* __restrict__ W3r,
    const float* __restrict__ W4l, const float* __restrict__ W4r,
    unsigned short* __restrict__ wb1, unsigned short* __restrict__ wb2,
    unsigned short* __restrict__ wb3, unsigned short* __restrict__ wb4,
    int* __restrict__ deg, int* __restrict__ eix) {
  int blk = blockIdx.x;
  if (blk < ADJ_BLK) {
    // padded-adjacency build: deg pre-zeroed by memset before this kernel
    int e = blk * 256 + threadIdx.x;
    int d = edst[e];
    int pos = atomicAdd(&deg[d], 1);
    if (pos < DSTRIDE) eix[(size_t)d * DSTRIDE + pos] = esrc[e];
  } else if (blk < ADJ_BLK + PW1_BLK) {
    pack_w_seg(blk - ADJ_BLK, W1l, W1r, wb1, 320, 8500, 8512, 640);
  } else if (blk < ADJ_BLK + PW1_BLK + PW2_BLK) {
    pack_w_seg(blk - ADJ_BLK - PW1_BLK, W2l, W2r, wb2, 180, 320, 320, 384);
  } else if (blk < ADJ_BLK + PW1_BLK + PW2_BLK + PW3_BLK) {
    pack_w_seg(blk - ADJ_BLK - PW1_BLK - PW2_BLK, W3l, W3r, wb3, 90, 180, 192, 256);
  } else {
    pack_w_seg(blk - ADJ_BLK - PW1_BLK - PW2_BLK - PW3_BLK, W4l, W4r, wb4,
               50, 90, 128, 128);
  }
}

// ======= layer-1 GEMM: 64x64 tiles, NO K-split (whole grid co-resident) =====
// C = A[M,8500->8512] @ B[N,8512]^T. Grid (64,10) = 640 blocks; LDS 24 KB ->
// 6 blocks/CU -> all 640 resident (capacity 1536): cross-block latency hiding
// does the pipelining (m97 lesson -- no manual fences).
// A staged RAW fp32 via async16: LDS dest lane-linear; ROTATED per-lane global
// source (16B block at phys pos p holds logical quad (p-row)&15). Fragment
// read = 2x ds_read_b128 + 8 cvt (VALU is idle). B = proven bf16 path.
__global__ __launch_bounds__(256) void gemm_f32a(const float* __restrict__ X,
                                                 const unsigned short* __restrict__ B,
                                                 float* __restrict__ C,
                                                 const float* __restrict__ zpad,
                                                 int N, int M) {
  const int K = 8512, KS = 133, FIN = 8500;
  __shared__ float As32[64 * 64];            // 16 KB fp32 A tile
  __shared__ unsigned short Bs[64 * 64];     // 8 KB bf16 B tile

  const int t = threadIdx.x;
  const int bm = blockIdx.x, bn = blockIdx.y;
  const int lane = t & 63;
  const int wave = t >> 6;
  const int wm = (wave & 1) * 32, wn = (wave >> 1) * 32;
  const int l16 = lane & 15, quad = lane >> 4;

  f32x4 acc[2][2];
#pragma unroll
  for (int i = 0; i < 2; ++i)
#pragma unroll
    for (int j = 0; j < 2; ++j) acc[i][j] = (f32x4){0.f, 0.f, 0.f, 0.f};

  // A staging: 4 calls; call ch: thread t covers row ch*16 + (t>>4), phys
  // 16B-block pos = t&15, which holds logical quad lg = (pos - row) & 15.
  int rowA[4], lgA[4];
  const float* gA[4];
#pragma unroll
  for (int ch = 0; ch < 4; ++ch) {
    int row = ch * 16 + (t >> 4);
    int lg = ((t & 15) - row) & 15;
    rowA[ch] = row; lgA[ch] = lg;
    gA[ch] = X + (size_t)(bm * 64 + row) * FIN + lg * 4;
  }
  // B staging: 2 calls; rows t>>3 and t>>3+32, 16B block t&7.
  const int srow = t >> 3;
  const int scol = (t & 7) * 8;
  const unsigned short* Bbase = B + (size_t)(bn * 64) * K + scol;

  for (int kt = 0; kt < KS; ++kt) {
    if (kt < 132) {
#pragma unroll
      for (int ch = 0; ch < 4; ++ch)
        async16(gA[ch] + (size_t)kt * 64, &As32[rowA[ch] * 64 + (t & 15) * 4]);
    } else {   // K tail: logical quads >= 13 start at col 8500 -> zero pad
#pragma unroll
      for (int ch = 0; ch < 4; ++ch) {
        const float* s = (lgA[ch] < 13) ? gA[ch] + (size_t)kt * 64 : zpad;
        async16(s, &As32[rowA[ch] * 64 + (t & 15) * 4]);
      }
    }
#pragma unroll
    for (int p = 0; p < 2; ++p) {
      int row = p * 32 + srow;
      async16(Bbase + (size_t)row * K + kt * 64, &Bs[row * 64 + scol]);
    }
    __syncthreads();
#pragma unroll
    for (int kh = 0; kh < 2; ++kh) {
      const int q2 = (kh * 4 + quad) * 2;               // logical quad pair
      bf16x8 af[2], bfr[2];
#pragma unroll
      for (int i = 0; i < 2; ++i) {
        int row = wm + i * 16 + l16;
        f32x4 a0 = *(const f32x4*)&As32[row * 64 + ((q2 + row) & 15) * 4];
        f32x4 a1 = *(const f32x4*)&As32[row * 64 + ((q2 + 1 + row) & 15) * 4];
        bf16x8 c;
#pragma unroll
        for (int o = 0; o < 4; ++o) { c[o] = (__bf16)a0[o]; c[o + 4] = (__bf16)a1[o]; }
        af[i] = c;
      }
#pragma unroll
      for (int j = 0; j < 2; ++j) {
        int row = wn + j * 16 + l16;
        int s8 = ((kh * 4 + quad + row) & 7) * 8;       // B unrotate
        bfr[j] = *(const bf16x8*)&Bs[row * 64 + s8];
      }
#pragma unroll
      for (int i = 0; i < 2; ++i)
#pragma unroll
        for (int j = 0; j < 2; ++j)
          acc[i][j] = __builtin_amdgcn_mfma_f32_16x16x32_bf16(af[i], bfr[j], acc[i][j], 0, 0, 0);
    }
    __syncthreads();
  }

#pragma unroll
  for (int i = 0; i < 2; ++i) {
    int rbase = bm * 64 + wm + i * 16 + quad * 4;
#pragma unroll
    for (int j = 0; j < 2; ++j) {
      int col = bn * 64 + wn + j * 16 + l16;
      float* cp = C + (size_t)rbase * N + col;
#pragma unroll
      for (int r = 0; r < 4; ++r) cp[(size_t)r * N] = acc[i][j][r];
    }
  }
}

// ---------------- bf16 MFMA GEMM (layers 2-4): C = A[M,K] @ B[N,K]^T --------
__global__ __launch_bounds__(256) void gemm_bt(const unsigned short* __restrict__ A,
                                               const unsigned short* __restrict__ B,
                                               float* __restrict__ C, int N, int K,
                                               int M) {
  __shared__ unsigned short smem[2 * 128 * 64];
  unsigned short* As = smem;
  unsigned short* Bs = smem + 128 * 64;

  const int t = threadIdx.x;
  const int bm = blockIdx.x, bn = blockIdx.y;
  const int lane = t & 63;
  const int wave = t >> 6;
  const int wm = (wave & 1) * 64, wn = (wave >> 1) * 64;
  const int l16 = lane & 15, quad = lane >> 4;

  const int ksteps = K >> 6;

  f32x4 acc[4][4];
#pragma unroll
  for (int i = 0; i < 4; ++i)
#pragma unroll
    for (int j = 0; j < 4; ++j) acc[i][j] = (f32x4){0.f, 0.f, 0.f, 0.f};

  const int srow = t >> 3;
  const int scol = (t & 7) * 8;
  const unsigned short* Abase = A + (size_t)(bm * 128) * K + scol;
  const unsigned short* Bbase = B + (size_t)(bn * 128) * K + scol;

  for (int kt = 0; kt < ksteps; ++kt) {
    const unsigned short* Ag = Abase + kt * 64;
    const unsigned short* Bg = Bbase + kt * 64;
#pragma unroll
    for (int p = 0; p < 4; ++p) {
      int row = p * 32 + srow;
      async16(Ag + (size_t)row * K, &As[row * 64 + scol]);
    }
#pragma unroll
    for (int p = 0; p < 4; ++p) {
      int row = p * 32 + srow;
      async16(Bg + (size_t)row * K, &Bs[row * 64 + scol]);
    }
    __syncthreads();
#pragma unroll
    for (int kh = 0; kh < 2; ++kh) {
      const int s8 = ((kh * 4 + quad + l16) & 7) * 8;   // unrotate
      bf16x8 af[4], bfr[4];
#pragma unroll
      for (int i = 0; i < 4; ++i)
        af[i] = *(const bf16x8*)&As[(wm + i * 16 + l16) * 64 + s8];
#pragma unroll
      for (int j = 0; j < 4; ++j)
        bfr[j] = *(const bf16x8*)&Bs[(wn + j * 16 + l16) * 64 + s8];
#pragma unroll
      for (int i = 0; i < 4; ++i)
#pragma unroll
        for (int j = 0; j < 4; ++j)
          acc[i][j] = __builtin_amdgcn_mfma_f32_16x16x32_bf16(af[i], bfr[j], acc[i][j], 0, 0, 0);
    }
    __syncthreads();
  }

#pragma unroll
  for (int i = 0; i < 4; ++i) {
    int rbase = bm * 128 + wm + i * 16 + quad * 4;
#pragma unroll
    for (int j = 0; j < 4; ++j) {
      int col = bn * 128 + wn + j * 16 + l16;
      float* cp = C + (size_t)rbase * N + col;
#pragma unroll
      for (int r = 0; r < 4; ++r) cp[(size_t)r * N] = acc[i][j][r];
    }
  }
}

// ---------------- fused mean-aggregate + root + bias + leaky ----------------
// block (64,4): tx = feature quad, ty = edge stripe; padded adjacency.
// In-block loop over 64-f4 feature stripes (stages edge list once per node).
__global__ __launch_bounds__(256) void sage_agg(
    const float* __restrict__ y, const int* __restrict__ deg,
    const int* __restrict__ eix, const float* __restrict__ bias,
    float* __restrict__ z, int F, int ldy) {
  int i = blockIdx.x;
  int tx = threadIdx.x, ty = threadIdx.y;
  __shared__ int se[DSTRIDE];
  __shared__ float red[3][64][4];
  int d = deg[i]; if (d > DSTRIDE) d = DSTRIDE;
  // stage edge list (d <= 96 -> one pass with 256 threads)
  {
    int lt = ty * 64 + tx;
    if (lt < d) se[lt] = eix[(size_t)i * DSTRIDE + lt];
  }
  __syncthreads();
  int nfb = (F + 255) >> 8;
  for (int fb = 0; fb < nfb; ++fb) {
    int f4 = (fb * 64 + tx) * 4;
    bool active = (f4 < F);
    f32x4 s = {0.f, 0.f, 0.f, 0.f};
    if (active) {
      const float* yb = y + f4;
      int e = ty;
      for (; e + 4 < d; e += 8) {   // 2x unroll: two independent loads in flight
        f32x4 a = *(const f32x4*)&yb[(size_t)se[e] * ldy];
        f32x4 b = *(const f32x4*)&yb[(size_t)se[e + 4] * ldy];
        s += a; s += b;
      }
      if (e < d) s += *(const f32x4*)&yb[(size_t)se[e] * ldy];
    }
    if (ty > 0) *(f32x4*)red[ty - 1][tx] = s;
    __syncthreads();
    if (ty == 0 && active) {
      s += *(const f32x4*)red[0][tx];
      s += *(const f32x4*)red[1][tx];
      s += *(const f32x4*)red[2][tx];
      float inv = 1.f / (float)(d > 1 ? d : 1);
      int cnt = F - f4; if (cnt > 4) cnt = 4;
      const float* yr = &y[(size_t)i * ldy + F + f4];
      float* zo = &z[(size_t)i * F + f4];
      for (int j = 0; j < cnt; ++j) {
        float w = s[j] * inv + yr[j] + bias[f4 + j];
        zo[j] = (w >= 0.f) ? w : LEAKY * w;
      }
    }
    if (fb + 1 < nfb) __syncthreads();   // red reuse barrier
  }
}

// ---------------- batchnorm: row-major partial sums + fused finalize --------

__global__ __launch_bounds__(256) void bn_part(const float* __restrict__ z,
                                               float* __restrict__ sums, int F) {
  int tx = threadIdx.x, ty = threadIdx.y;      // block (64,4)
  int f = blockIdx.x * 64 + tx;
  float s = 0.f, s2 = 0.f;
  if (f < F) {
    int r0 = blockIdx.y * 512 + ty * 128;
    for (int j = 0; j < 128; ++j) {
      float v = z[(size_t)(r0 + j) * F + f];
      s += v; s2 += v * v;
    }
  }
  __shared__ float ls[4][64], ls2[4][64];
  ls[ty][tx] = s; ls2[ty][tx] = s2;
  __syncthreads();
  if (ty == 0 && f < F) {
    float S  = ls[0][tx] + ls[1][tx] + ls[2][tx] + ls[3][tx];
    float S2 = ls2[0][tx] + ls2[1][tx] + ls2[2][tx] + ls2[3][tx];
    atomicAdd(&sums[f], S);
    atomicAdd(&sums[F + f], S2);
  }
}

// normalize -> next layer's rotated bf16 input (finalizes BN from sums)
__global__ void bn_norm8(const float* __restrict__ z, const float* __restrict__ sums,
                         unsigned short* __restrict__ xout, int F, int Kp) {
  int nb = Kp >> 3;
  int idx = blockIdx.x * 256 + threadIdx.x;    // exact grid
  int row = idx / nb, kb = idx - row * nb;
  int g = kb >> 3, b = kb & 7;
  int dkb = (g << 3) | ((b + row) & 7);
  u16x8 st;
#pragma unroll
  for (int o = 0; o < 8; ++o) {
    int k = kb * 8 + o;
    float v = 0.f;
    if (k < F) {
      float m  = sums[k] * (1.f / NN);
      float var = sums[F + k] * (1.f / NN) - m * m;
      float rs = rsqrtf(var + BN_EPS);
      v = (z[(size_t)row * F + k] - m) * rs;
    }
    st[o] = f2bf(v);
  }
  *(u16x8*)&xout[(size_t)row * Kp + dkb * 8] = st;
}

// ---------------- pool (BN folded in) + 3 FC layers ----------------
// block (64,4): ty stripes the 256 rows of each batch segment (was serial).
__global__ void pool_fc(const float* __restrict__ z,  // [4096, 50] pre-BN
                        const float* __restrict__ sums,
                        const float* __restrict__ Wf1, const float* __restrict__ bf1,
                        const float* __restrict__ Wf2, const float* __restrict__ bf2,
                        const float* __restrict__ Wf3, const float* __restrict__ bf3,
                        float* __restrict__ out) {
  __shared__ float ps[4][50];
  __shared__ float pool[50];
  __shared__ float h1[32], h2[16];
  int b = blockIdx.x, tx = threadIdx.x, ty = threadIdx.y;
  if (tx < 50) {
    float s = 0.f;
    int r0 = b * 256 + ty * 64;
    for (int r = 0; r < 64; ++r) s += z[(size_t)(r0 + r) * 50 + tx];
    ps[ty][tx] = s;
  }
  __syncthreads();
  if (ty == 0 && tx < 50) {
    float s = ps[0][tx] + ps[1][tx] + ps[2][tx] + ps[3][tx];
    float m  = sums[tx] * (1.f / NN);
    float var = sums[50 + tx] * (1.f / NN) - m * m;
    float rs = rsqrtf(var + BN_EPS);
    pool[tx] = (s - 256.f * m) * rs;   // sum of normalized = (sum - n*m)*rs
  }
  __syncthreads();
  if (ty == 0 && tx < 32) {
    float s = bf1[tx];
    for (int f = 0; f < 50; ++f) s += pool[f] * Wf1[tx * 50 + f];
    h1[tx] = s;
  }
  __syncthreads();
  if (ty == 0 && tx < 16) {
    float s = bf2[tx];
    for (int f = 0; f < 32; ++f) s += h1[f] * Wf2[tx * 32 + f];
    h2[tx] = s;
  }
  __syncthreads();
  if (ty == 0 && tx == 0) {
    float s = bf3[0];
    for (int f = 0; f < 16; ++f) s += h2[f] * Wf3[f];
    out[b] = s;
  }
}

// ---------------- host ----------------

extern "C" void kernel_launch(void* const* d_in, const int* in_sizes, int n_in,
                              void* d_out, int out_size, void* d_ws, size_t ws_size,
                              hipStream_t stream) {
  const float* x_in = (const float*)d_in[0];
  const int* ei = (const int*)d_in[1];      // int32 per harness contract
  const float* W1l = (const float*)d_in[2];
  const float* b1  = (const float*)d_in[3];
  const float* W1r = (const float*)d_in[4];
  const float* W2l = (const float*)d_in[5];
  const float* b2  = (const float*)d_in[6];
  const float* W2r = (const float*)d_in[7];
  const float* W3l = (const float*)d_in[8];
  const float* b3  = (const float*)d_in[9];
  const float* W3r = (const float*)d_in[10];
  const float* W4l = (const float*)d_in[11];
  const float* b4  = (const float*)d_in[12];
  const float* W4r = (const float*)d_in[13];
  const float* Wf1 = (const float*)d_in[14];
  const float* bf1 = (const float*)d_in[15];
  const float* Wf2 = (const float*)d_in[16];
  const float* bf2 = (const float*)d_in[17];
  const float* Wf3 = (const float*)d_in[18];
  const float* bf3 = (const float*)d_in[19];
  float* out = (float*)d_out;
  (void)in_sizes; (void)n_in; (void)out_size;

  char* ws = (char*)d_ws;
  size_t off = 0;
  auto alloc = [&](size_t bytes) -> void* {
    void* p = ws + off;
    off = (off + bytes + 255) & ~(size_t)255;
    return p;
  };
  unsigned short* xbf = (unsigned short*)alloc((size_t)NN * 320 * 2);  // layers 2-4 A
  unsigned short* wb1 = (unsigned short*)alloc((size_t)640 * 8512 * 2);
  unsigned short* wb2 = (unsigned short*)alloc((size_t)384 * 320 * 2);
  unsigned short* wb3 = (unsigned short*)alloc((size_t)256 * 192 * 2);
  unsigned short* wb4 = (unsigned short*)alloc((size_t)128 * 128 * 2);
  float* z    = (float*)alloc((size_t)NN * 320 * 4);
  // contiguous zero region: deg + bnsum + zpad
  int* deg    = (int*)alloc(NN * 4);
  float* bnsum = (float*)alloc(1280 * 4);
  float* zpad  = (float*)alloc(256);
  int* eix    = (int*)alloc((size_t)NN * DSTRIDE * 4);
  float* y    = (float*)alloc((size_t)NN * 640 * 4);   // single y, no K-split
  if (off > ws_size) return;
  float* bns1 = bnsum;             // 2*320
  float* bns2 = bnsum + 640;       // 2*180
  float* bns3 = bnsum + 1000;      // 2*90
  float* bns4 = bnsum + 1180;      // 2*50

  hipMemsetAsync(deg, 0, NN * 4 + 1280 * 4 + 256, stream);

  setup_all<<<dim3(SETUP_BLK), dim3(256), 0, stream>>>(
      ei, ei + NE, W1l, W1r, W2l, W2r, W3l, W3r, W4l, W4r,
      wb1, wb2, wb3, wb4, deg, eix);

  // ---- layer 1: K=8512, 64x64 tiles, grid fully co-resident, no K-split ----
  gemm_f32a<<<dim3(64, 10), dim3(256), 0, stream>>>(x_in, wb1, y, zpad, 640, NN);
  sage_agg<<<dim3(NN), dim3(64, 4), 0, stream>>>(y, deg, eix, b1, z, 320, 640);
  bn_part<<<dim3(5, 8), dim3(64, 4), 0, stream>>>(z, bns1, 320);
  bn_norm8<<<dim3(NN * 40 / 256), dim3(256), 0, stream>>>(z, bns1, xbf, 320, 320);

  // ---- layer 2: K=320, N=384 ----
  gemm_bt<<<dim3(32, 3, 1), dim3(256), 0, stream>>>(xbf, wb2, y, 384, 320, NN);
  sage_agg<<<dim3(NN), dim3(64, 4), 0, stream>>>(y, deg, eix, b2, z, 180, 384);
  bn_part<<<dim3(3, 8), dim3(64, 4), 0, stream>>>(z, bns2, 180);
  bn_norm8<<<dim3(NN * 24 / 256), dim3(256), 0, stream>>>(z, bns2, xbf, 180, 192);

  // ---- layer 3: K=192, N=256 ----
  gemm_bt<<<dim3(32, 2, 1), dim3(256), 0, stream>>>(xbf, wb3, y, 256, 192, NN);
  sage_agg<<<dim3(NN), dim3(64, 4), 0, stream>>>(y, deg, eix, b3, z, 90, 256);
  bn_part<<<dim3(2, 8), dim3(64, 4), 0, stream>>>(z, bns3, 90);
  bn_norm8<<<dim3(NN * 16 / 256), dim3(256), 0, stream>>>(z, bns3, xbf, 90, 128);

  // ---- layer 4: K=128, N=128 ----
  gemm_bt<<<dim3(32, 1, 1), dim3(256), 0, stream>>>(xbf, wb4, y, 128, 128, NN);
  sage_agg<<<dim3(NN), dim3(64, 4), 0, stream>>>(y, deg, eix, b4, z, 50, 128);
  bn_part<<<dim3(1, 8), dim3(64, 4), 0, stream>>>(z, bns4, 50);

  // ---- pool (BN folded) + FC ----
  pool_fc<<<dim3(16), dim3(64, 4), 0, stream>>>(z, bns4, Wf1, bf1, Wf2, bf2, Wf3, bf3, out);
}

// Round 9
// 470.560 us; speedup vs baseline: 1.1431x; 1.0745x over previous
//
#include <hip/hip_runtime.h>
#include <stdint.h>

#define NN 4096
#define NE 65536
#define LEAKY 0.01f
#define BN_EPS 1e-5f
#define DSTRIDE 96   // padded adjacency stride (mean deg 16, 12+ sigma margin)

typedef float f32x4 __attribute__((ext_vector_type(4)));
typedef __bf16 bf16x8 __attribute__((ext_vector_type(8)));
typedef unsigned short u16x8 __attribute__((ext_vector_type(8)));
typedef unsigned short u16x4 __attribute__((ext_vector_type(4)));

static __device__ __forceinline__ unsigned short f2bf(float v) {
  unsigned int u = __float_as_uint(v);
  u += 0x7fff + ((u >> 16) & 1);   // RNE; inputs are finite
  return (unsigned short)(u >> 16);
}

static __device__ __forceinline__ f32x4 bf4f(u16x4 v) {
  f32x4 r;
#pragma unroll
  for (int j = 0; j < 4; ++j) r[j] = __uint_as_float(((unsigned)v[j]) << 16);
  return r;
}

typedef __attribute__((address_space(1))) void gvoid;
typedef __attribute__((address_space(3))) void lvoid;

static __device__ __forceinline__ void async16(const void* g, void* l) {
  __builtin_amdgcn_global_load_lds((gvoid*)(uintptr_t)g,
                                   (lvoid*)(uint32_t)(uintptr_t)l, 16, 0, 0);
}

// ======================= setup: W packs + adjacency build ===================
// bf16 GEMM-input layout: within each 64-col K-group, row r's 16B block b is
// stored at block (b + r) & 7 (LDS de-conflict rotation; GEMM unrotates).
// x_in is NOT packed: layer-1 GEMM converts fp32->bf16 in-staging (R3 design).

static __device__ __forceinline__ void pack_w_seg(int lblk, const float* __restrict__ Wl,
                                                  const float* __restrict__ Wr,
                                                  unsigned short* __restrict__ dst,
                                                  int Fout, int Fin, int Kp, int Np) {
  int nb = Kp >> 3;
  int idx = lblk * 256 + threadIdx.x;
  if (idx >= Np * nb) return;
  int row = idx / nb, kb = idx - row * nb;
  int g = kb >> 3, b = kb & 7;
  int dkb = (g << 3) | ((b + row) & 7);
  const float* src = nullptr;
  if (row < Fout)          src = Wl + (size_t)row * Fin;
  else if (row < 2 * Fout) src = Wr + (size_t)(row - Fout) * Fin;
  u16x8 st;
#pragma unroll
  for (int o = 0; o < 8; ++o) {
    int k = kb * 8 + o;
    float v = (src && k < Fin) ? src[k] : 0.f;
    st[o] = f2bf(v);
  }
  *(u16x8*)&dst[(size_t)row * Kp + dkb * 8] = st;
}

#define ADJ_BLK    256   // 65536/256 (first: atomic tail overlaps pack work)
#define PW1_BLK   2660   // 640*1064/256
#define PW2_BLK     60
#define PW3_BLK     24
#define PW4_BLK      8
#define SETUP_BLK (ADJ_BLK + PW1_BLK + PW2_BLK + PW3_BLK + PW4_BLK)

__global__ __launch_bounds__(256) void setup_all(
    const int* __restrict__ esrc, const int* __restrict__ edst,
    const float* __restrict__ W1l, const float* __restrict__ W1r,
    const float* __restrict__ W2l, const float* __restrict__ W2r,
    const float* __restrict__ W3l, const float* __restrict__ W3r,
    const float* __restrict__ W4l, const float* __restrict__ W4r,
    unsigned short* __restrict__ wb1, unsigned short* __restrict__ wb2,
    unsigned short* __restrict__ wb3, unsigned short* __restrict__ wb4,
    int* __restrict__ deg, int* __restrict__ eix) {
  int blk = blockIdx.x;
  if (blk < ADJ_BLK) {
    // padded-adjacency build: deg pre-zeroed by memset before this kernel
    int e = blk * 256 + threadIdx.x;
    int d = edst[e];
    int pos = atomicAdd(&deg[d], 1);
    if (pos < DSTRIDE) eix[(size_t)d * DSTRIDE + pos] = esrc[e];
  } else if (blk < ADJ_BLK + PW1_BLK) {
    pack_w_seg(blk - ADJ_BLK, W1l, W1r, wb1, 320, 8500, 8512, 640);
  } else if (blk < ADJ_BLK + PW1_BLK + PW2_BLK) {
    pack_w_seg(blk - ADJ_BLK - PW1_BLK, W2l, W2r, wb2, 180, 320, 320, 384);
  } else if (blk < ADJ_BLK + PW1_BLK + PW2_BLK + PW3_BLK) {
    pack_w_seg(blk - ADJ_BLK - PW1_BLK - PW2_BLK, W3l, W3r, wb3, 90, 180, 192, 256);
  } else {
    pack_w_seg(blk - ADJ_BLK - PW1_BLK - PW2_BLK - PW3_BLK, W4l, W4r, wb4,
               50, 90, 128, 128);
  }
}

// ======= layer-1 GEMM (R3-proven, 122us): A = x_in fp32 cvt in staging ======
// C = A[M,8500->8512] @ B[N,8512]^T, K-split partials over blockIdx.z.
// A: global fp32 -> regs (prefetch k+1 under compute k) -> cvt -> rotated
//    ds_write. B: async global_load_lds, double-buffered.
__global__ __launch_bounds__(256) void gemm_f32a(const float* __restrict__ X,
                                                 const unsigned short* __restrict__ B,
                                                 float* __restrict__ C, int N, int M) {
  const int K = 8512, KS = 133, FIN = 8500;
  __shared__ unsigned short smem[3 * 128 * 64];   // As + Bs[2] = 48 KB
  unsigned short* As = smem;

  const int t = threadIdx.x;
  const int bm = blockIdx.x, bn = blockIdx.y;
  const int lane = t & 63;
  const int wave = t >> 6;
  const int wm = (wave & 1) * 64, wn = (wave >> 1) * 64;
  const int l16 = lane & 15, quad = lane >> 4;

  const int gz = (int)gridDim.z, z = (int)blockIdx.z;
  const int per = KS / gz, rem = KS % gz;
  const int k0 = z * per + (z < rem ? z : rem);
  const int k1 = k0 + per + (z < rem ? 1 : 0);

  f32x4 acc[4][4];
#pragma unroll
  for (int i = 0; i < 4; ++i)
#pragma unroll
    for (int j = 0; j < 4; ++j) acc[i][j] = (f32x4){0.f, 0.f, 0.f, 0.f};

  const int srow = t >> 3;          // 0..31
  const int bblk = t & 7;           // 16B block within 64-col group
  const int scol = bblk * 8;
  const float* Xb = X + (size_t)(bm * 128) * FIN;
  const unsigned short* Bbase = B + (size_t)(bn * 128) * K + scol;

  float va[4][8];
  auto loadA = [&](int kt) {
    int gc = kt * 64 + scol;
#pragma unroll
    for (int p = 0; p < 4; ++p) {
      const float* ap = Xb + (size_t)(p * 32 + srow) * FIN + gc;
      if (gc + 8 <= FIN) {
        f32x4 a = *(const f32x4*)ap;
        f32x4 b2 = *(const f32x4*)(ap + 4);
#pragma unroll
        for (int o = 0; o < 4; ++o) { va[p][o] = a[o]; va[p][o + 4] = b2[o]; }
      } else {
#pragma unroll
        for (int o = 0; o < 8; ++o) va[p][o] = (gc + o < FIN) ? ap[o] : 0.f;
      }
    }
  };
  auto writeA = [&]() {
#pragma unroll
    for (int p = 0; p < 4; ++p) {
      int row = p * 32 + srow;
      int rot = ((bblk + row) & 7) * 8;
      bf16x8 bv;
#pragma unroll
      for (int o = 0; o < 8; ++o) bv[o] = (__bf16)va[p][o];
      *(bf16x8*)&As[row * 64 + rot] = bv;
    }
  };
  auto stageB = [&](int kt, int bb) {
    unsigned short* Bd = smem + 128 * 64 + bb * 128 * 64;
#pragma unroll
    for (int p = 0; p < 4; ++p) {
      int row = p * 32 + srow;
      async16(Bbase + (size_t)row * K + kt * 64, &Bd[row * 64 + scol]);
    }
  };

  // prologue: stage k0 (A via regs, B async into buf 0)
  loadA(k0);
  stageB(k0, 0);
  writeA();
  __syncthreads();

  int bb = 0;
  for (int kt = k0; kt < k1; ++kt) {
    bool more = (kt + 1 < k1);
    if (more) {
      loadA(kt + 1);            // global loads in flight under MFMA
      stageB(kt + 1, bb ^ 1);   // async into idle B buffer
    }
    const unsigned short* Bs = smem + 128 * 64 + bb * 128 * 64;
#pragma unroll
    for (int kh = 0; kh < 2; ++kh) {
      const int s8 = ((kh * 4 + quad + l16) & 7) * 8;   // unrotate
      bf16x8 af[4], bfr[4];
#pragma unroll
      for (int i = 0; i < 4; ++i)
        af[i] = *(const bf16x8*)&As[(wm + i * 16 + l16) * 64 + s8];
#pragma unroll
      for (int j = 0; j < 4; ++j)
        bfr[j] = *(const bf16x8*)&Bs[(wn + j * 16 + l16) * 64 + s8];
#pragma unroll
      for (int i = 0; i < 4; ++i)
#pragma unroll
        for (int j = 0; j < 4; ++j)
          acc[i][j] = __builtin_amdgcn_mfma_f32_16x16x32_bf16(af[i], bfr[j], acc[i][j], 0, 0, 0);
    }
    __syncthreads();            // compute done; As reusable
    if (more) {
      writeA();                 // cvt + rotated ds_write (waits va loads)
      __syncthreads();          // staging visible
      bb ^= 1;
    }
  }

  float* Cb = C + (size_t)blockIdx.z * M * N;
#pragma unroll
  for (int i = 0; i < 4; ++i) {
    int rbase = bm * 128 + wm + i * 16 + quad * 4;
#pragma unroll
    for (int j = 0; j < 4; ++j) {
      int col = bn * 128 + wn + j * 16 + l16;
      float* cp = Cb + (size_t)rbase * N + col;
#pragma unroll
      for (int r = 0; r < 4; ++r) cp[(size_t)r * N] = acc[i][j][r];
    }
  }
}

// -------- bf16 MFMA GEMM (layers 2-4): C[bf16] = A[M,K] @ B[N,K]^T ----------
__global__ __launch_bounds__(256) void gemm_bt(const unsigned short* __restrict__ A,
                                               const unsigned short* __restrict__ B,
                                               unsigned short* __restrict__ C, int N,
                                               int K, int M) {
  __shared__ unsigned short smem[2 * 128 * 64];
  unsigned short* As = smem;
  unsigned short* Bs = smem + 128 * 64;

  const int t = threadIdx.x;
  const int bm = blockIdx.x, bn = blockIdx.y;
  const int lane = t & 63;
  const int wave = t >> 6;
  const int wm = (wave & 1) * 64, wn = (wave >> 1) * 64;
  const int l16 = lane & 15, quad = lane >> 4;

  const int ksteps = K >> 6;

  f32x4 acc[4][4];
#pragma unroll
  for (int i = 0; i < 4; ++i)
#pragma unroll
    for (int j = 0; j < 4; ++j) acc[i][j] = (f32x4){0.f, 0.f, 0.f, 0.f};

  const int srow = t >> 3;
  const int scol = (t & 7) * 8;
  const unsigned short* Abase = A + (size_t)(bm * 128) * K + scol;
  const unsigned short* Bbase = B + (size_t)(bn * 128) * K + scol;

  for (int kt = 0; kt < ksteps; ++kt) {
    const unsigned short* Ag = Abase + kt * 64;
    const unsigned short* Bg = Bbase + kt * 64;
#pragma unroll
    for (int p = 0; p < 4; ++p) {
      int row = p * 32 + srow;
      async16(Ag + (size_t)row * K, &As[row * 64 + scol]);
    }
#pragma unroll
    for (int p = 0; p < 4; ++p) {
      int row = p * 32 + srow;
      async16(Bg + (size_t)row * K, &Bs[row * 64 + scol]);
    }
    __syncthreads();
#pragma unroll
    for (int kh = 0; kh < 2; ++kh) {
      const int s8 = ((kh * 4 + quad + l16) & 7) * 8;   // unrotate
      bf16x8 af[4], bfr[4];
#pragma unroll
      for (int i = 0; i < 4; ++i)
        af[i] = *(const bf16x8*)&As[(wm + i * 16 + l16) * 64 + s8];
#pragma unroll
      for (int j = 0; j < 4; ++j)
        bfr[j] = *(const bf16x8*)&Bs[(wn + j * 16 + l16) * 64 + s8];
#pragma unroll
      for (int i = 0; i < 4; ++i)
#pragma unroll
        for (int j = 0; j < 4; ++j)
          acc[i][j] = __builtin_amdgcn_mfma_f32_16x16x32_bf16(af[i], bfr[j], acc[i][j], 0, 0, 0);
    }
    __syncthreads();
  }

#pragma unroll
  for (int i = 0; i < 4; ++i) {
    int rbase = bm * 128 + wm + i * 16 + quad * 4;
#pragma unroll
    for (int j = 0; j < 4; ++j) {
      int col = bn * 128 + wn + j * 16 + l16;
      unsigned short* cp = C + (size_t)rbase * N + col;
#pragma unroll
      for (int r = 0; r < 4; ++r) cp[(size_t)r * N] = f2bf(acc[i][j][r]);
    }
  }
}

// sum nz fp32 K-split slabs -> bf16 y; grid exact NN*640/8/256
__global__ void reduceNbf(const float* __restrict__ yp, unsigned short* __restrict__ y,
                          int nz) {
  int idx = blockIdx.x * 256 + threadIdx.x;    // 8 elems per thread
  const f32x4* p = (const f32x4*)yp;
  const int S = NN * 640 / 4;
  int i2 = idx * 2;
  f32x4 a = p[i2], b = p[i2 + 1];
  for (int sl = 1; sl < nz; ++sl) {
    a += p[i2 + (size_t)sl * S];
    b += p[i2 + 1 + (size_t)sl * S];
  }
  u16x8 st;
#pragma unroll
  for (int o = 0; o < 4; ++o) { st[o] = f2bf(a[o]); st[o + 4] = f2bf(b[o]); }
  *(u16x8*)&y[(size_t)idx * 8] = st;
}

// ---------------- fused mean-aggregate + root + bias + leaky ----------------
// y is bf16 (halved gather traffic). block (64,4): tx = feature quad,
// ty = edge stripe; padded adjacency; in-block loop over feature stripes.
__global__ __launch_bounds__(256) void sage_agg(
    const unsigned short* __restrict__ y, const int* __restrict__ deg,
    const int* __restrict__ eix, const float* __restrict__ bias,
    float* __restrict__ z, int F, int ldy) {
  int i = blockIdx.x;
  int tx = threadIdx.x, ty = threadIdx.y;
  __shared__ int se[DSTRIDE];
  __shared__ float red[3][64][4];
  int d = deg[i]; if (d > DSTRIDE) d = DSTRIDE;
  // stage edge list (d <= 96 -> one pass with 256 threads)
  {
    int lt = ty * 64 + tx;
    if (lt < d) se[lt] = eix[(size_t)i * DSTRIDE + lt];
  }
  __syncthreads();
  int nfb = (F + 255) >> 8;
  for (int fb = 0; fb < nfb; ++fb) {
    int f4 = (fb * 64 + tx) * 4;
    bool active = (f4 < F);
    f32x4 s = {0.f, 0.f, 0.f, 0.f};
    if (active) {
      const unsigned short* yb = y + f4;
      int e = ty;
      for (; e + 4 < d; e += 8) {   // 2x unroll: two independent loads in flight
        u16x4 a = *(const u16x4*)&yb[(size_t)se[e] * ldy];
        u16x4 b = *(const u16x4*)&yb[(size_t)se[e + 4] * ldy];
        s += bf4f(a); s += bf4f(b);
      }
      if (e < d) s += bf4f(*(const u16x4*)&yb[(size_t)se[e] * ldy]);
    }
    if (ty > 0) *(f32x4*)red[ty - 1][tx] = s;
    __syncthreads();
    if (ty == 0 && active) {
      s += *(const f32x4*)red[0][tx];
      s += *(const f32x4*)red[1][tx];
      s += *(const f32x4*)red[2][tx];
      float inv = 1.f / (float)(d > 1 ? d : 1);
      int cnt = F - f4; if (cnt > 4) cnt = 4;
      const unsigned short* yr = &y[(size_t)i * ldy + F + f4];
      float* zo = &z[(size_t)i * F + f4];
      for (int j = 0; j < cnt; ++j) {
        float rv = __uint_as_float(((unsigned)yr[j]) << 16);
        float w = s[j] * inv + rv + bias[f4 + j];
        zo[j] = (w >= 0.f) ? w : LEAKY * w;
      }
    }
    if (fb + 1 < nfb) __syncthreads();   // red reuse barrier
  }
}

// ---------------- batchnorm: row-major partial sums + fused finalize --------

__global__ __launch_bounds__(256) void bn_part(const float* __restrict__ z,
                                               float* __restrict__ sums, int F) {
  int tx = threadIdx.x, ty = threadIdx.y;      // block (64,4)
  int f = blockIdx.x * 64 + tx;
  float s = 0.f, s2 = 0.f;
  if (f < F) {
    int r0 = blockIdx.y * 512 + ty * 128;
    for (int j = 0; j < 128; ++j) {
      float v = z[(size_t)(r0 + j) * F + f];
      s += v; s2 += v * v;
    }
  }
  __shared__ float ls[4][64], ls2[4][64];
  ls[ty][tx] = s; ls2[ty][tx] = s2;
  __syncthreads();
  if (ty == 0 && f < F) {
    float S  = ls[0][tx] + ls[1][tx] + ls[2][tx] + ls[3][tx];
    float S2 = ls2[0][tx] + ls2[1][tx] + ls2[2][tx] + ls2[3][tx];
    atomicAdd(&sums[f], S);
    atomicAdd(&sums[F + f], S2);
  }
}

// normalize -> next layer's rotated bf16 input (finalizes BN from sums)
__global__ void bn_norm8(const float* __restrict__ z, const float* __restrict__ sums,
                         unsigned short* __restrict__ xout, int F, int Kp) {
  int nb = Kp >> 3;
  int idx = blockIdx.x * 256 + threadIdx.x;    // exact grid
  int row = idx / nb, kb = idx - row * nb;
  int g = kb >> 3, b = kb & 7;
  int dkb = (g << 3) | ((b + row) & 7);
  u16x8 st;
#pragma unroll
  for (int o = 0; o < 8; ++o) {
    int k = kb * 8 + o;
    float v = 0.f;
    if (k < F) {
      float m  = sums[k] * (1.f / NN);
      float var = sums[F + k] * (1.f / NN) - m * m;
      float rs = rsqrtf(var + BN_EPS);
      v = (z[(size_t)row * F + k] - m) * rs;
    }
    st[o] = f2bf(v);
  }
  *(u16x8*)&xout[(size_t)row * Kp + dkb * 8] = st;
}

// ---------------- pool (BN folded in) + 3 FC layers ----------------
// block (64,4): ty stripes the 256 rows of each batch segment.
__global__ void pool_fc(const float* __restrict__ z,  // [4096, 50] pre-BN
                        const float* __restrict__ sums,
                        const float* __restrict__ Wf1, const float* __restrict__ bf1,
                        const float* __restrict__ Wf2, const float* __restrict__ bf2,
                        const float* __restrict__ Wf3, const float* __restrict__ bf3,
                        float* __restrict__ out) {
  __shared__ float ps[4][50];
  __shared__ float pool[50];
  __shared__ float h1[32], h2[16];
  int b = blockIdx.x, tx = threadIdx.x, ty = threadIdx.y;
  if (tx < 50) {
    float s = 0.f;
    int r0 = b * 256 + ty * 64;
    for (int r = 0; r < 64; ++r) s += z[(size_t)(r0 + r) * 50 + tx];
    ps[ty][tx] = s;
  }
  __syncthreads();
  if (ty == 0 && tx < 50) {
    float s = ps[0][tx] + ps[1][tx] + ps[2][tx] + ps[3][tx];
    float m  = sums[tx] * (1.f / NN);
    float var = sums[50 + tx] * (1.f / NN) - m * m;
    float rs = rsqrtf(var + BN_EPS);
    pool[tx] = (s - 256.f * m) * rs;   // sum of normalized = (sum - n*m)*rs
  }
  __syncthreads();
  if (ty == 0 && tx < 32) {
    float s = bf1[tx];
    for (int f = 0; f < 50; ++f) s += pool[f] * Wf1[tx * 50 + f];
    h1[tx] = s;
  }
  __syncthreads();
  if (ty == 0 && tx < 16) {
    float s = bf2[tx];
    for (int f = 0; f < 32; ++f) s += h1[f] * Wf2[tx * 32 + f];
    h2[tx] = s;
  }
  __syncthreads();
  if (ty == 0 && tx == 0) {
    float s = bf3[0];
    for (int f = 0; f < 16; ++f) s += h2[f] * Wf3[f];
    out[b] = s;
  }
}

// ---------------- host ----------------

extern "C" void kernel_launch(void* const* d_in, const int* in_sizes, int n_in,
                              void* d_out, int out_size, void* d_ws, size_t ws_size,
                              hipStream_t stream) {
  const float* x_in = (const float*)d_in[0];
  const int* ei = (const int*)d_in[1];      // int32 per harness contract
  const float* W1l = (const float*)d_in[2];
  const float* b1  = (const float*)d_in[3];
  const float* W1r = (const float*)d_in[4];
  const float* W2l = (const float*)d_in[5];
  const float* b2  = (const float*)d_in[6];
  const float* W2r = (const float*)d_in[7];
  const float* W3l = (const float*)d_in[8];
  const float* b3  = (const float*)d_in[9];
  const float* W3r = (const float*)d_in[10];
  const float* W4l = (const float*)d_in[11];
  const float* b4  = (const float*)d_in[12];
  const float* W4r = (const float*)d_in[13];
  const float* Wf1 = (const float*)d_in[14];
  const float* bf1 = (const float*)d_in[15];
  const float* Wf2 = (const float*)d_in[16];
  const float* bf2 = (const float*)d_in[17];
  const float* Wf3 = (const float*)d_in[18];
  const float* bf3 = (const float*)d_in[19];
  float* out = (float*)d_out;
  (void)in_sizes; (void)n_in; (void)out_size;

  char* ws = (char*)d_ws;
  size_t off = 0;
  auto alloc = [&](size_t bytes) -> void* {
    void* p = ws + off;
    off = (off + bytes + 255) & ~(size_t)255;
    return p;
  };
  unsigned short* xbf = (unsigned short*)alloc((size_t)NN * 320 * 2);  // layers 2-4 A
  unsigned short* wb1 = (unsigned short*)alloc((size_t)640 * 8512 * 2);
  unsigned short* wb2 = (unsigned short*)alloc((size_t)384 * 320 * 2);
  unsigned short* wb3 = (unsigned short*)alloc((size_t)256 * 192 * 2);
  unsigned short* wb4 = (unsigned short*)alloc((size_t)128 * 128 * 2);
  float* z    = (float*)alloc((size_t)NN * 320 * 4);
  // contiguous zero region: deg + bnsum
  int* deg    = (int*)alloc(NN * 4);
  float* bnsum = (float*)alloc(1280 * 4);
  int* eix    = (int*)alloc((size_t)NN * DSTRIDE * 4);
  unsigned short* ybf = (unsigned short*)alloc((size_t)NN * 640 * 2);  // bf16 y
  const size_t YS = (size_t)NN * 640 * 4;   // one fp32 K-split slab
  float* yp = (float*)(ws + off);           // partial slabs last
  const int nz = 4;
  if (off + (size_t)nz * YS > ws_size) return;
  float* bns1 = bnsum;             // 2*320
  float* bns2 = bnsum + 640;       // 2*180
  float* bns3 = bnsum + 1000;      // 2*90
  float* bns4 = bnsum + 1180;      // 2*50

  hipMemsetAsync(deg, 0, NN * 4 + 1280 * 4, stream);

  setup_all<<<dim3(SETUP_BLK), dim3(256), 0, stream>>>(
      ei, ei + NE, W1l, W1r, W2l, W2r, W3l, W3r, W4l, W4r,
      wb1, wb2, wb3, wb4, deg, eix);

  // ---- layer 1: K=8512 (fp32 A in-staging cvt), K-split nz + bf16 reduce ----
  gemm_f32a<<<dim3(32, 5, nz), dim3(256), 0, stream>>>(x_in, wb1, yp, 640, NN);
  reduceNbf<<<dim3(NN * 640 / 8 / 256), dim3(256), 0, stream>>>(yp, ybf, nz);
  sage_agg<<<dim3(NN), dim3(64, 4), 0, stream>>>(ybf, deg, eix, b1, z, 320, 640);
  bn_part<<<dim3(5, 8), dim3(64, 4), 0, stream>>>(z, bns1, 320);
  bn_norm8<<<dim3(NN * 40 / 256), dim3(256), 0, stream>>>(z, bns1, xbf, 320, 320);

  // ---- layer 2: K=320, N=384 ----
  gemm_bt<<<dim3(32, 3, 1), dim3(256), 0, stream>>>(xbf, wb2, ybf, 384, 320, NN);
  sage_agg<<<dim3(NN), dim3(64, 4), 0, stream>>>(ybf, deg, eix, b2, z, 180, 384);
  bn_part<<<dim3(3, 8), dim3(64, 4), 0, stream>>>(z, bns2, 180);
  bn_norm8<<<dim3(NN * 24 / 256), dim3(256), 0, stream>>>(z, bns2, xbf, 180, 192);

  // ---- layer 3: K=192, N=256 ----
  gemm_bt<<<dim3(32, 2, 1), dim3(256), 0, stream>>>(xbf, wb3, ybf, 256, 192, NN);
  sage_agg<<<dim3(NN), dim3(64, 4), 0, stream>>>(ybf, deg, eix, b3, z, 90, 256);
  bn_part<<<dim3(2, 8), dim3(64, 4), 0, stream>>>(z, bns3, 90);
  bn_norm8<<<dim3(NN * 16 / 256), dim3(256), 0, stream>>>(z, bns3, xbf, 90, 128);

  // ---- layer 4: K=128, N=128 ----
  gemm_bt<<<dim3(32, 1, 1), dim3(256), 0, stream>>>(xbf, wb4, ybf, 128, 128, NN);
  sage_agg<<<dim3(NN), dim3(64, 4), 0, stream>>>(ybf, deg, eix, b4, z, 50, 128);
  bn_part<<<dim3(1, 8), dim3(64, 4), 0, stream>>>(z, bns4, 50);

  // ---- pool (BN folded) + FC ----
  pool_fc<<<dim3(16), dim3(64, 4), 0, stream>>>(z, bns4, Wf1, bf1, Wf2, bf2, Wf3, bf3, out);
}